// Round 5
// baseline (181.643 us; speedup 1.0000x reference)
//
#include <hip/hip_runtime.h>
#include <hip/hip_bf16.h>

#define NL    64
#define DIN   512
#define DOUT  512
#define BATCH 1024

#define BM 128
#define BN 128
#define KH  256    // K staged per half
#define NSL 8      // 32-k slices per half

typedef short short8 __attribute__((ext_vector_type(8)));
typedef float f32x4  __attribute__((ext_vector_type(4)));

__device__ __forceinline__ unsigned int pk2(float a, float b) {
    // v_cvt_pk_bf16_f32 (RNE)
    __hip_bfloat162 h = __float22bfloat162_rn(make_float2(a, b));
    unsigned int r;
    __builtin_memcpy(&r, &h, 4);
    return r;
}

__global__ __launch_bounds__(256, 2) void nlinear_kernel(
        const float* __restrict__ x, const float* __restrict__ w,
        const float* __restrict__ bias, float* __restrict__ out) {
    // B (= w, transposed) only: [col][k-half] bf16, 64 KB.
    // 16B-slot swizzle within a row: slot ^= (col & 7).
    __shared__ unsigned short Bs[BN * KH];

    const int tid = threadIdx.x;
    const int bid = blockIdx.x;
    // XCD swizzle: 2048 = 8 x 256; each XCD owns 8 whole layers
    const int nb    = (bid & 7) * 256 + (bid >> 3);
    const int layer = nb >> 5;
    const int tile  = nb & 31;
    const int bm0   = (tile >> 2) * BM;
    const int bn0   = (tile & 3) * BN;

    const int wid  = tid >> 6;
    const int lane = tid & 63;
    const int wr   = wid >> 1, wc = wid & 1;   // 2x2 waves, 64x64 tile each
    const int lrow = lane & 15;
    const int lkb  = lane >> 4;

    // B staging ownership: 4 cols x 8 contiguous k per round
    const int bcol0 = (tid & 31) << 2;   // 0..124
    const int bkt   = tid >> 5;          // 0..7

    const size_t XS = (size_t)NL * DIN;  // x row stride in floats
    const float* xrow = x + (size_t)(bm0 + wr * 64 + lrow) * XS + (size_t)layer * DIN;
    const float* wb   = w + (size_t)layer * DIN * DOUT + bn0;

    f32x4 acc[4][4];
#pragma unroll
    for (int i = 0; i < 4; ++i)
#pragma unroll
        for (int j = 0; j < 4; ++j) acc[i][j] = (f32x4){0.f, 0.f, 0.f, 0.f};

#pragma unroll
    for (int h = 0; h < 2; ++h) {
        if (h) {
            // all waves done reading half 0 before restage
            __builtin_amdgcn_s_barrier();
            __builtin_amdgcn_sched_barrier(0);   // keep ds_writes below the barrier
        }

        // ---- stage B half h: w[h*KH + r*64 + bkt*8 + i][bn0 + bcol0 + j] ----
#pragma unroll
        for (int r = 0; r < 4; ++r) {
            f32x4 bv[8];
#pragma unroll
            for (int i = 0; i < 8; ++i)
                bv[i] = *reinterpret_cast<const f32x4*>(
                    wb + (size_t)(h * KH + r * 64 + bkt * 8 + i) * DOUT + bcol0);
#pragma unroll
            for (int j = 0; j < 4; ++j) {
                const int c = bcol0 + j;
                uint4 wv;
                wv.x = pk2(bv[0][j], bv[1][j]);
                wv.y = pk2(bv[2][j], bv[3][j]);
                wv.z = pk2(bv[4][j], bv[5][j]);
                wv.w = pk2(bv[6][j], bv[7][j]);
                const int slot = (r * 8 + bkt) ^ (c & 7);
                *reinterpret_cast<uint4*>(&Bs[c * KH + slot * 8]) = wv;
            }
        }
        asm volatile("s_waitcnt lgkmcnt(0)" ::: "memory");
        __builtin_amdgcn_sched_barrier(0);
        __builtin_amdgcn_s_barrier();
        __builtin_amdgcn_sched_barrier(0);

        // ---- compute 8 slices, barrier-free; A direct global->reg, 1-slice prefetch ----
        f32x4 pr[2][4][2];
#pragma unroll
        for (int mi = 0; mi < 4; ++mi) {
            const float* p = xrow + (size_t)(mi * 16) * XS + h * KH + lkb * 8;
            pr[0][mi][0] = *reinterpret_cast<const f32x4*>(p);
            pr[0][mi][1] = *reinterpret_cast<const f32x4*>(p + 4);
        }
#pragma unroll
        for (int s = 0; s < NSL; ++s) {
            if (s + 1 < NSL) {
#pragma unroll
                for (int mi = 0; mi < 4; ++mi) {
                    const float* p = xrow + (size_t)(mi * 16) * XS
                                   + h * KH + (s + 1) * 32 + lkb * 8;
                    pr[(s + 1) & 1][mi][0] = *reinterpret_cast<const f32x4*>(p);
                    pr[(s + 1) & 1][mi][1] = *reinterpret_cast<const f32x4*>(p + 4);
                }
            }
            short8 af[4], bfr[4];
#pragma unroll
            for (int mi = 0; mi < 4; ++mi) {
                const f32x4 a0 = pr[s & 1][mi][0];
                const f32x4 a1 = pr[s & 1][mi][1];
                uint4 uv;
                uv.x = pk2(a0[0], a0[1]);
                uv.y = pk2(a0[2], a0[3]);
                uv.z = pk2(a1[0], a1[1]);
                uv.w = pk2(a1[2], a1[3]);
                __builtin_memcpy(&af[mi], &uv, 16);
            }
#pragma unroll
            for (int ni = 0; ni < 4; ++ni) {
                const int c = wc * 64 + ni * 16 + lrow;
                const int slot = (s * 4 + lkb) ^ (c & 7);
                bfr[ni] = *reinterpret_cast<const short8*>(&Bs[c * KH + slot * 8]);
            }
            __builtin_amdgcn_s_setprio(1);
#pragma unroll
            for (int mi = 0; mi < 4; ++mi)
#pragma unroll
                for (int ni = 0; ni < 4; ++ni)
                    acc[mi][ni] = __builtin_amdgcn_mfma_f32_16x16x32_bf16(
                        af[mi], bfr[ni], acc[mi][ni], 0, 0, 0);
            __builtin_amdgcn_s_setprio(0);
        }
    }

    // ---- epilogue: + bias, fp32 store ----
    const float* bb = bias + (size_t)layer * DOUT + bn0;
    float* ob = out + (size_t)bm0 * (NL * DOUT) + (size_t)layer * DOUT + bn0;
#pragma unroll
    for (int mi = 0; mi < 4; ++mi) {
#pragma unroll
        for (int ni = 0; ni < 4; ++ni) {
            const int col = wc * 64 + ni * 16 + lrow;
            const float bval = bb[col];
#pragma unroll
            for (int r = 0; r < 4; ++r) {
                const int row = wr * 64 + mi * 16 + lkb * 4 + r;
                ob[(size_t)row * (NL * DOUT) + col] = acc[mi][ni][r] + bval;
            }
        }
    }
}

extern "C" void kernel_launch(void* const* d_in, const int* in_sizes, int n_in,
                              void* d_out, int out_size, void* d_ws, size_t ws_size,
                              hipStream_t stream) {
    const float* x  = (const float*)d_in[0];
    const float* w  = (const float*)d_in[1];
    const float* b  = (const float*)d_in[2];
    float* out      = (float*)d_out;

    dim3 grid(NL * (BATCH / BM) * (DOUT / BN));   // 2048
    dim3 block(256);
    hipLaunchKernelGGL(nlinear_kernel, grid, block, 0, stream, x, w, b, out);
}

// Round 6
// 136.771 us; speedup vs baseline: 1.3281x; 1.3281x over previous
//
#include <hip/hip_runtime.h>
#include <hip/hip_bf16.h>

#define NL    64
#define DIN   512
#define DOUT  512
#define BATCH 1024

#define BM 128
#define BN 128
#define BK 64
#define NK (DIN / BK)   // 8

typedef short short8 __attribute__((ext_vector_type(8)));
typedef float f32x4  __attribute__((ext_vector_type(4)));

__device__ __forceinline__ unsigned int pk2(float a, float b) {
    // v_cvt_pk_bf16_f32 (RNE)
    __hip_bfloat162 h = __float22bfloat162_rn(make_float2(a, b));
    unsigned int r;
    __builtin_memcpy(&r, &h, 4);
    return r;
}

__global__ __launch_bounds__(256, 2) void nlinear_kernel(
        const float* __restrict__ x, const float* __restrict__ w,
        const float* __restrict__ bias, float* __restrict__ out) {
    // Double-buffered bf16 tiles [row][k], 64-elem (128 B) rows.
    // 16B-slot XOR swizzle: stored_slot = logical_slot ^ (row & 7).
    __shared__ unsigned short As[2][BM * BK];   // 2 x 16 KB
    __shared__ unsigned short Bs[2][BN * BK];   // 2 x 16 KB

    const int tid = threadIdx.x;
    const int bid = blockIdx.x;
    // XCD swizzle: 2048 = 8 XCDs x 256 blocks; each XCD owns 8 whole layers
    const int nb    = (bid & 7) * 256 + (bid >> 3);
    const int layer = nb >> 5;
    const int tile  = nb & 31;
    const int bm0   = (tile >> 2) * BM;
    const int bn0   = (tile & 3) * BN;

    const int wid  = tid >> 6;
    const int lane = tid & 63;
    const int wr   = wid >> 1, wc = wid & 1;   // 2x2 waves, 64x64 tile each
    const int lrow = lane & 15;
    const int lkb  = lane >> 4;
    const int lsw  = lrow & 7;                 // frag-read XOR key

    // A-stage: 8 lanes/row, rows arow8+32j (j=0..3); lane owns 8 floats at k=alane*8
    const int arow8 = tid >> 3;                // 0..31
    const int alane = tid & 7;
    const int aslot = (alane ^ (arow8 & 7)) << 3;   // constant per thread
    // B-stage: gk = k-octet 0..7, gn = col-group 0..31 (4 cols each)
    const int gk = tid & 7;
    const int gn = tid >> 3;

    const size_t XS = (size_t)NL * DIN;        // x row stride (floats)
    const float* xb = x + (size_t)bm0 * XS + (size_t)layer * DIN;
    const float* wb = w + (size_t)layer * DIN * DOUT + bn0;
    const float* aptr0 = xb + (size_t)arow8 * XS + alane * 8;
    const float* bptr0 = wb + (size_t)(gk * 8) * DOUT + gn * 4;

    f32x4 acc[4][4];
#pragma unroll
    for (int i = 0; i < 4; ++i)
#pragma unroll
        for (int j = 0; j < 4; ++j) acc[i][j] = (f32x4){0.f, 0.f, 0.f, 0.f};

    f32x4 av[8], bv[8];

    auto issue = [&](int kt) {
#pragma unroll
        for (int j = 0; j < 4; ++j) {
            const float* p = aptr0 + (size_t)(32 * j) * XS + kt * BK;
            av[2 * j]     = *reinterpret_cast<const f32x4*>(p);
            av[2 * j + 1] = *reinterpret_cast<const f32x4*>(p + 4);
        }
#pragma unroll
        for (int i = 0; i < 8; ++i)
            bv[i] = *reinterpret_cast<const f32x4*>(
                bptr0 + (size_t)(kt * BK + i) * DOUT);
    };

    auto cvtwrite = [&](int b) {
#pragma unroll
        for (int j = 0; j < 4; ++j) {
            uint4 wv;
            wv.x = pk2(av[2*j][0],   av[2*j][1]);
            wv.y = pk2(av[2*j][2],   av[2*j][3]);
            wv.z = pk2(av[2*j+1][0], av[2*j+1][1]);
            wv.w = pk2(av[2*j+1][2], av[2*j+1][3]);
            *reinterpret_cast<uint4*>(&As[b][(arow8 + 32 * j) * BK + aslot]) = wv;
        }
#pragma unroll
        for (int j = 0; j < 4; ++j) {
            const int c = gn * 4 + j;
            uint4 wv;
            wv.x = pk2(bv[0][j], bv[1][j]);
            wv.y = pk2(bv[2][j], bv[3][j]);
            wv.z = pk2(bv[4][j], bv[5][j]);
            wv.w = pk2(bv[6][j], bv[7][j]);
            *reinterpret_cast<uint4*>(&Bs[b][c * BK + ((gk ^ (c & 7)) << 3)]) = wv;
        }
    };

    auto fragA = [&](int b, int s, short8* af) {
#pragma unroll
        for (int mi = 0; mi < 4; ++mi) {
            const int row = wr * 64 + mi * 16 + lrow;
            af[mi] = *reinterpret_cast<const short8*>(
                &As[b][row * BK + (((s * 4 + lkb) ^ lsw) << 3)]);
        }
    };
    auto fragB = [&](int b, int s, short8* bf) {
#pragma unroll
        for (int ni = 0; ni < 4; ++ni) {
            const int col = wc * 64 + ni * 16 + lrow;
            bf[ni] = *reinterpret_cast<const short8*>(
                &Bs[b][col * BK + (((s * 4 + lkb) ^ lsw) << 3)]);
        }
    };

#define BARRIER() do { \
        asm volatile("s_waitcnt lgkmcnt(0)" ::: "memory"); \
        __builtin_amdgcn_sched_barrier(0); \
        __builtin_amdgcn_s_barrier(); \
        __builtin_amdgcn_sched_barrier(0); } while (0)

#define MFMA16(AF, BF) do { \
        __builtin_amdgcn_s_setprio(1); \
        _Pragma("unroll") \
        for (int mi = 0; mi < 4; ++mi) \
        _Pragma("unroll") \
            for (int ni = 0; ni < 4; ++ni) \
                acc[mi][ni] = __builtin_amdgcn_mfma_f32_16x16x32_bf16( \
                    AF[mi], BF[ni], acc[mi][ni], 0, 0, 0); \
        __builtin_amdgcn_s_setprio(0); } while (0)

    // ---- prologue: tile0 -> buf0, tile1 loads in flight ----
    issue(0);
    cvtwrite(0);
    issue(1);
    BARRIER();

    // ---- steady state: 1 barrier per K-step ----
#pragma unroll 1
    for (int k = 0; k < NK - 2; ++k) {
        short8 af0[4], bf0[4], af1[4], bf1[4];
        fragA(k & 1, 0, af0);      // ds_reads issue immediately (no vmem dep)
        fragB(k & 1, 0, bf0);
        cvtwrite((k + 1) & 1);     // waits vmcnt on tile k+1 (1 full iter in flight)
        issue(k + 2);              // next loads take flight under MFMA below
        MFMA16(af0, bf0);
        fragA(k & 1, 1, af1);
        fragB(k & 1, 1, bf1);
        MFMA16(af1, bf1);
        BARRIER();
    }

    // ---- k = NK-2: no more loads to issue ----
    {
        const int k = NK - 2;
        short8 af0[4], bf0[4], af1[4], bf1[4];
        fragA(k & 1, 0, af0);
        fragB(k & 1, 0, bf0);
        cvtwrite((k + 1) & 1);
        MFMA16(af0, bf0);
        fragA(k & 1, 1, af1);
        fragB(k & 1, 1, bf1);
        MFMA16(af1, bf1);
        BARRIER();
    }
    // ---- k = NK-1: compute only ----
    {
        const int k = NK - 1;
        short8 af0[4], bf0[4], af1[4], bf1[4];
        fragA(k & 1, 0, af0);
        fragB(k & 1, 0, bf0);
        MFMA16(af0, bf0);
        fragA(k & 1, 1, af1);
        fragB(k & 1, 1, bf1);
        MFMA16(af1, bf1);
    }

    // ---- epilogue: + bias, fp32 store ----
    const float* bb = bias + (size_t)layer * DOUT + bn0;
    float* ob = out + (size_t)bm0 * (NL * DOUT) + (size_t)layer * DOUT + bn0;
#pragma unroll
    for (int mi = 0; mi < 4; ++mi) {
#pragma unroll
        for (int ni = 0; ni < 4; ++ni) {
            const int col = wc * 64 + ni * 16 + lrow;
            const float bval = bb[col];
#pragma unroll
            for (int r = 0; r < 4; ++r) {
                const int row = wr * 64 + mi * 16 + lkb * 4 + r;
                ob[(size_t)row * (NL * DOUT) + col] = acc[mi][ni][r] + bval;
            }
        }
    }
#undef BARRIER
#undef MFMA16
}

extern "C" void kernel_launch(void* const* d_in, const int* in_sizes, int n_in,
                              void* d_out, int out_size, void* d_ws, size_t ws_size,
                              hipStream_t stream) {
    const float* x  = (const float*)d_in[0];
    const float* w  = (const float*)d_in[1];
    const float* b  = (const float*)d_in[2];
    float* out      = (float*)d_out;

    dim3 grid(NL * (BATCH / BM) * (DOUT / BN));   // 2048
    dim3 block(256);
    hipLaunchKernelGGL(nlinear_kernel, grid, block, 0, stream, x, w, b, out);
}

// Round 7
// 128.199 us; speedup vs baseline: 1.4169x; 1.0669x over previous
//
#include <hip/hip_runtime.h>
#include <hip/hip_bf16.h>

#define NL    64
#define DIN   512
#define DOUT  512
#define BATCH 1024

#define BM 128
#define BN 128
#define BK 32
#define NK (DIN / BK)   // 16

typedef short short8 __attribute__((ext_vector_type(8)));
typedef float f32x4  __attribute__((ext_vector_type(4)));

__device__ __forceinline__ unsigned int pk2(float a, float b) {
    // v_cvt_pk_bf16_f32 (RNE)
    __hip_bfloat162 h = __float22bfloat162_rn(make_float2(a, b));
    unsigned int r;
    __builtin_memcpy(&r, &h, 4);
    return r;
}

__global__ __launch_bounds__(256, 3) void nlinear_kernel(
        const float* __restrict__ x, const float* __restrict__ w,
        const float* __restrict__ bias, float* __restrict__ out) {
    // Double-buffered bf16 tiles [row][k], 32-elem (64 B) rows = 4 x 16B slots.
    // XOR swizzle at 16B granularity: stored_slot = logical_slot ^ (row & 3).
    __shared__ unsigned short As[2][BM * BK];   // 2 x 8 KB
    __shared__ unsigned short Bs[2][BN * BK];   // 2 x 8 KB

    const int tid = threadIdx.x;
    const int bid = blockIdx.x;
    // XCD swizzle: 2048 = 8 XCDs x 256 blocks; each XCD owns 8 whole layers
    const int nb    = (bid & 7) * 256 + (bid >> 3);
    const int layer = nb >> 5;
    const int tile  = nb & 31;
    const int bm0   = (tile >> 2) * BM;
    const int bn0   = (tile & 3) * BN;

    const int wid  = tid >> 6;
    const int lane = tid & 63;
    const int wr   = wid >> 1, wc = wid & 1;   // 2x2 waves, 64x64 tile each
    const int lrow = lane & 15;
    const int lkb  = lane >> 4;                // k-octet selector 0..3

    // A-stage: thread owns rows {arow, arow+64}, 8 consecutive k at ak
    const int arow  = tid >> 2;                // 0..63
    const int ak    = (tid & 3) << 3;          // 0,8,16,24
    const int aslot = (((tid & 3) ^ (arow & 3)) << 3);  // ushort offset, const/thread
    // B-stage: gk = k-quad 0..7 (4 k each), gn = col-group 0..31 (4 cols each)
    const int gk = tid & 7;
    const int gn = tid >> 3;

    const size_t XS = (size_t)NL * DIN;        // x row stride (floats)
    const float* xb = x + (size_t)bm0 * XS + (size_t)layer * DIN;
    const float* wb = w + (size_t)layer * DIN * DOUT + bn0;
    const float* aptr0 = xb + (size_t)arow * XS + ak;
    const float* bptr0 = wb + (size_t)(gk * 4) * DOUT + gn * 4;

    f32x4 acc[4][4];
#pragma unroll
    for (int i = 0; i < 4; ++i)
#pragma unroll
        for (int j = 0; j < 4; ++j) acc[i][j] = (f32x4){0.f, 0.f, 0.f, 0.f};

    f32x4 av[4], bv[4];

    auto issue = [&](int kt) {
        const float* a0 = aptr0 + kt * BK;
        av[0] = *reinterpret_cast<const f32x4*>(a0);
        av[1] = *reinterpret_cast<const f32x4*>(a0 + 4);
        av[2] = *reinterpret_cast<const f32x4*>(a0 + 64 * XS);
        av[3] = *reinterpret_cast<const f32x4*>(a0 + 64 * XS + 4);
#pragma unroll
        for (int i = 0; i < 4; ++i)
            bv[i] = *reinterpret_cast<const f32x4*>(
                bptr0 + (size_t)(kt * BK + i) * DOUT);
    };

    auto cvtwrite = [&](int b) {
        // A: 2x ds_write_b128 (8 bf16 = one 16B slot each)
#pragma unroll
        for (int v = 0; v < 2; ++v) {
            uint4 wv;
            wv.x = pk2(av[2*v][0],   av[2*v][1]);
            wv.y = pk2(av[2*v][2],   av[2*v][3]);
            wv.z = pk2(av[2*v+1][0], av[2*v+1][1]);
            wv.w = pk2(av[2*v+1][2], av[2*v+1][3]);
            *reinterpret_cast<uint4*>(&As[b][(arow + 64 * v) * BK + aslot]) = wv;
        }
        // B transpose: 4x ds_write_b64; 16B slot = (gk>>1)^(c&3), 8B half = gk&1
#pragma unroll
        for (int j = 0; j < 4; ++j) {
            const int c = gn * 4 + j;
            uint2 wv;
            wv.x = pk2(bv[0][j], bv[1][j]);
            wv.y = pk2(bv[2][j], bv[3][j]);
            const int off = c * BK + (((gk >> 1) ^ (c & 3)) << 3) + ((gk & 1) << 2);
            *reinterpret_cast<uint2*>(&Bs[b][off]) = wv;
        }
    };

    auto fragA = [&](int b, short8* af) {
#pragma unroll
        for (int mi = 0; mi < 4; ++mi) {
            const int row = wr * 64 + mi * 16 + lrow;
            af[mi] = *reinterpret_cast<const short8*>(
                &As[b][row * BK + ((lkb ^ (row & 3)) << 3)]);
        }
    };
    auto fragB = [&](int b, short8* bf) {
#pragma unroll
        for (int ni = 0; ni < 4; ++ni) {
            const int col = wc * 64 + ni * 16 + lrow;
            bf[ni] = *reinterpret_cast<const short8*>(
                &Bs[b][col * BK + ((lkb ^ (col & 3)) << 3)]);
        }
    };

#define BARRIER() do { \
        asm volatile("s_waitcnt lgkmcnt(0)" ::: "memory"); \
        __builtin_amdgcn_sched_barrier(0); \
        __builtin_amdgcn_s_barrier(); \
        __builtin_amdgcn_sched_barrier(0); } while (0)

#define MFMA16(AF, BF) do { \
        __builtin_amdgcn_s_setprio(1); \
        _Pragma("unroll") \
        for (int mi = 0; mi < 4; ++mi) \
        _Pragma("unroll") \
            for (int ni = 0; ni < 4; ++ni) \
                acc[mi][ni] = __builtin_amdgcn_mfma_f32_16x16x32_bf16( \
                    AF[mi], BF[ni], acc[mi][ni], 0, 0, 0); \
        __builtin_amdgcn_s_setprio(0); } while (0)

    // ---- prologue: tile0 -> buf0, tile1 loads in flight ----
    issue(0);
    cvtwrite(0);
    issue(1);
    BARRIER();

    // ---- steady state: 1 no-drain barrier per K-step ----
#pragma unroll 1
    for (int k = 0; k < NK - 2; ++k) {
        short8 af[4], bf[4];
        fragA(k & 1, af);          // ds_reads issue immediately (no vmem dep)
        fragB(k & 1, bf);
        cvtwrite((k + 1) & 1);     // waits vmcnt on tile k+1 (1 full iter in flight)
        issue(k + 2);              // next loads take flight under MFMA below
        MFMA16(af, bf);
        BARRIER();
    }
    // ---- k = NK-2: no more loads to issue ----
    {
        short8 af[4], bf[4];
        fragA((NK - 2) & 1, af);
        fragB((NK - 2) & 1, bf);
        cvtwrite((NK - 1) & 1);
        MFMA16(af, bf);
        BARRIER();
    }
    // ---- k = NK-1: compute only ----
    {
        short8 af[4], bf[4];
        fragA((NK - 1) & 1, af);
        fragB((NK - 1) & 1, bf);
        MFMA16(af, bf);
    }

    // ---- epilogue: + bias, fp32 store ----
    const float* bb = bias + (size_t)layer * DOUT + bn0;
    float* ob = out + (size_t)bm0 * (NL * DOUT) + (size_t)layer * DOUT + bn0;
#pragma unroll
    for (int mi = 0; mi < 4; ++mi) {
#pragma unroll
        for (int ni = 0; ni < 4; ++ni) {
            const int col = wc * 64 + ni * 16 + lrow;
            const float bval = bb[col];
#pragma unroll
            for (int r = 0; r < 4; ++r) {
                const int row = wr * 64 + mi * 16 + lkb * 4 + r;
                ob[(size_t)row * (NL * DOUT) + col] = acc[mi][ni][r] + bval;
            }
        }
    }
#undef BARRIER
#undef MFMA16
}

extern "C" void kernel_launch(void* const* d_in, const int* in_sizes, int n_in,
                              void* d_out, int out_size, void* d_ws, size_t ws_size,
                              hipStream_t stream) {
    const float* x  = (const float*)d_in[0];
    const float* w  = (const float*)d_in[1];
    const float* b  = (const float*)d_in[2];
    float* out      = (float*)d_out;

    dim3 grid(NL * (BATCH / BM) * (DOUT / BN));   // 2048
    dim3 block(256);
    hipLaunchKernelGGL(nlinear_kernel, grid, block, 0, stream, x, w, b, out);
}